// Round 13
// baseline (137.431 us; speedup 1.0000x reference)
//
#include <hip/hip_runtime.h>
#include <hip/hip_fp16.h>
#include <stdint.h>

#define HH 512
#define WW 512
#define NPIX (HH*WW)
#define ALPHA_MIN_C (1.0f/255.0f)
#define ALPHA_MAX_C 0.99f
#define BLUR_C 0.3f
#define LOG2E 1.4426950408889634f

// ---------------- Kernel 1: partial stable-rank counts (no atomics) -----------
// rank[g] = #{ j : d[j] < d[g] or (d[j]==d[g] and j<g) }  (JAX stable argsort)
#define JSL 512
__global__ __launch_bounds__(256) void rank_kernel(const float* __restrict__ depths,
                                                   int N, int* __restrict__ partial) {
    __shared__ uint32_t sk[JSL];
    const int tid = threadIdx.x;
    const int ngb = N >> 8;                       // 32
    const int gb = blockIdx.x % ngb;
    const int jb = blockIdx.x / ngb;
    const int j0 = jb * JSL;
    for (int i = tid; i < JSL; i += 256)
        sk[i] = __float_as_uint(depths[j0 + i]);
    __syncthreads();
    const int g = gb * 256 + tid;
    const uint32_t mb = __float_as_uint(depths[g]);
    const int glim = g - j0;                      // tie j0+i < g  <=>  i < glim
    int cnt = 0;
    const uint4* sk4 = (const uint4*)sk;
#pragma unroll 8
    for (int q = 0; q < JSL / 4; ++q) {
        uint4 v = sk4[q];
        const int i4 = q * 4;
        cnt += (v.x < mb) || (v.x == mb && (i4 + 0) < glim);
        cnt += (v.y < mb) || (v.y == mb && (i4 + 1) < glim);
        cnt += (v.z < mb) || (v.z == mb && (i4 + 2) < glim);
        cnt += (v.w < mb) || (v.w == mb && (i4 + 3) < glim);
    }
    partial[jb * N + g] = cnt;
}

// ---------------- Kernel 2: prep + scatter into sorted order ------------------
// pP [pos] = (mx, my, bx, by)                 (AABB, used only by bin_kernel)
// pR0[pos] = (mx, my, iaF, ibF|icF f16x2)
// pR1[pos] = (lop, cr|cg f16x2, cb, 0)
// alpha = min(.99, exp2(iaF dx^2 + icF dy^2 + ibF dx dy + lop)), lop = log2(op)
// AABB exact marginal bound: alpha>=1/255 requires |dx|<=bx AND |dy|<=by.
__global__ __launch_bounds__(256) void prep_kernel(
    const float* __restrict__ means, const float* __restrict__ colors,
    const float* __restrict__ ops, const float* __restrict__ scales,
    const float* __restrict__ rots, const int* __restrict__ partial, int N,
    float4* __restrict__ pP, float4* __restrict__ pR0, float4* __restrict__ pR1) {
    int g = blockIdx.x * 256 + threadIdx.x;
    if (g >= N) return;
    int pos = 0;
#pragma unroll
    for (int s = 0; s < 16; ++s) pos += partial[s * N + g];
    float mx = means[2*g], my = means[2*g+1];
    float th = rots[g];
    float c = cosf(th), si = sinf(th);
    float sx = scales[2*g], sy = scales[2*g+1];
    float sx2 = sx*sx, sy2 = sy*sy;
    float A  = c*c*sx2 + si*si*sy2;
    float Cc = si*si*sx2 + c*c*sy2;
    float B  = c*si*(sx2 - sy2);
    float det = A*Cc - B*B;
    float A2 = A + BLUR_C, C2 = Cc + BLUR_C;      // dilated Sxx, Syy
    float det2 = A2*C2 - B*B;
    float op = ops[g] * sqrtf(fmaxf(det/det2, 0.0f));
    float invd = 1.0f/det2;
    float ia = C2*invd, ib = -B*invd, ic = A2*invd;       // Sigma^-1
    float iaF = -0.5f*LOG2E*ia, icF = -0.5f*LOG2E*ic, ibF = -LOG2E*ib;
    float bx, by, lop;
    if (op < ALPHA_MIN_C) {
        bx = -1.0f; by = -1.0f; lop = -128.0f;
    } else {
        float t = __logf(op * 255.0f);                    // ln(op/ALPHA_MIN) >= 0
        bx = sqrtf(fmaxf(2.0f * t * A2, 0.0f)) * 1.0001f + 0.1f;
        by = sqrtf(fmaxf(2.0f * t * C2, 0.0f)) * 1.0001f + 0.1f;
        lop = __log2f(op);
    }
    __half2 h2 = __floats2half2_rn(ibF, icF);
    unsigned ibic; __builtin_memcpy(&ibic, &h2, 4);
    __half2 cc = __floats2half2_rn(colors[3*g], colors[3*g+1]);
    unsigned crcg; __builtin_memcpy(&crcg, &cc, 4);
    pP [pos] = make_float4(mx, my, bx, by);
    pR0[pos] = make_float4(mx, my, iaF, __uint_as_float(ibic));
    pR1[pos] = make_float4(lop, __uint_as_float(crcg), colors[3*g+2], 0.0f);
}

// ---------------- Kernel 3: bitmask binning -----------------------------------
// For sorted gaussian p: set bit (p&1023) in mask of every tile whose pixel-
// center rect overlaps the AABB. Tile passes x iff
// (mx-bx-15.5)/16 <= tX <= (mx+bx-0.5)/16  (same floats as the old per-block
// test; +0.1 margin in bx swamps rounding). Bit order == depth order.
#define NSEG 8
#define SEGG 1024

__global__ __launch_bounds__(256) void bin_kernel(
    const float4* __restrict__ pP, uint32_t* __restrict__ masks, int N) {
    int p = blockIdx.x * 256 + threadIdx.x;
    if (p >= N) return;
    float4 a = pP[p];
    if (a.z < 0.0f) return;
    int tx0 = max(0,  (int)ceilf ((a.x - a.z - 15.5f) * 0.0625f));
    int tx1 = min(31, (int)floorf((a.x + a.z -  0.5f) * 0.0625f));
    int ty0 = max(0,  (int)ceilf ((a.y - a.w - 15.5f) * 0.0625f));
    int ty1 = min(31, (int)floorf((a.y + a.w -  0.5f) * 0.0625f));
    const int seg = p >> 10;
    const int bit = p & 1023;
    const uint32_t wi = bit >> 5;
    const uint32_t bm = 1u << (bit & 31);
    uint32_t* base = masks + (((uint32_t)seg << 10) * 32) + wi;
    for (int ty = ty0; ty <= ty1; ++ty)
        for (int tx = tx0; tx <= tx1; ++tx)
            atomicOr(base + (uint32_t)(ty*32 + tx) * 32, bm);
}

// ---------------- Kernel 4: depth-segmented blend (mask-driven) ---------------
// 8 seg x 1024 tiles = 8192 one-wave blocks, 4 px/lane (rows y,y+4,y+8,y+12).
// Block reads its 1024-bit mask, wave-scans set bits into an ordered LDS index
// list (2KB), then blends only the listed records via broadcast global loads
// (software-pipelined 1 ahead). No per-block segment scan, tiny LDS ->
// high occupancy. Segment (A_rgb,T) packed 4xf16; composite folds in order.
__device__ __forceinline__ uint2 packAT(float r, float g, float b, float t) {
    __half2 hrg = __floats2half2_rn(r, g);
    __half2 hbt = __floats2half2_rn(b, t);
    uint2 u;
    __builtin_memcpy(&u.x, &hrg, 4);
    __builtin_memcpy(&u.y, &hbt, 4);
    return u;
}

__global__ __launch_bounds__(64) void seg_blend_kernel(
    const float4* __restrict__ pR0, const float4* __restrict__ pR1,
    const uint32_t* __restrict__ masks, uint2* __restrict__ segbuf) {
    __shared__ uint16_t sIdx[SEGG];
    const int lane = threadIdx.x;                 // 0..63
    const int tile = blockIdx.x & 1023;
    const int seg  = blockIdx.x >> 10;            // 0..7
    const int tX = tile & 31, tY = tile >> 5;
    const int px = tX*16 + (lane & 15);
    const int py = tY*16 + (lane >> 4);           // rows 0..3 (+4k below)
    const float fx = px + 0.5f, fy = py + 0.5f;

    // ---- ordered index list from the mask ----
    uint32_t w = (lane < 32) ? masks[(((uint32_t)seg << 10) | tile)*32 + lane] : 0u;
    int pc = __popc(w);
    int inc = pc;
#pragma unroll
    for (int d = 1; d < 64; d <<= 1) {
        int t = __shfl_up(inc, d);
        if (lane >= d) inc += t;
    }
    const int M = __shfl(inc, 63);
    int off = inc - pc;
    const int bword = lane << 5;
    while (w) {
        int b = __ffs(w) - 1;
        w &= w - 1;
        sIdx[off++] = (uint16_t)(bword + b);
    }
    __threadfence_block();                        // lgkmcnt(0): list visible

    float T0=1.f,T1=1.f,T2=1.f,T3=1.f;
    float aR0=0.f,aG0=0.f,aB0=0.f;
    float aR1=0.f,aG1=0.f,aB1=0.f;
    float aR2=0.f,aG2=0.f,aB2=0.f;
    float aR3=0.f,aG3=0.f,aB3=0.f;
    const int gb = seg << 10;

    if (M > 0) {
        int gi = gb + sIdx[0];
        float4 r0 = pR0[gi];
        float4 r1 = pR1[gi];
        for (int i = 0; i < M; ++i) {
            // issue next record's loads before evaluating current (pipelined)
            int giN = gi;
            if (i + 1 < M) giN = gb + sIdx[i + 1];
            float4 r0N = pR0[giN];
            float4 r1N = pR1[giN];
            float dx = fx - r0.x;
            float dy = fy - r0.y;
            unsigned hh = __float_as_uint(r0.w);
            __half2 h2; __builtin_memcpy(&h2, &hh, 4);
            float ibv = __half2float(h2.x);
            float icv = __half2float(h2.y);
            float bse = fmaf(r0.z, dx*dx, r1.x);     // iaF*dx^2 + lop
            float pb  = ibv * dx;                    // ibF*dx (shared by 4 rows)
            float d1 = dy + 4.0f, d2 = dy + 8.0f, d3 = dy + 12.0f;
            float p0 = fmaf(icv, dy*dy, fmaf(pb, dy, bse));
            float p1 = fmaf(icv, d1*d1, fmaf(pb, d1, bse));
            float p2 = fmaf(icv, d2*d2, fmaf(pb, d2, bse));
            float p3 = fmaf(icv, d3*d3, fmaf(pb, d3, bse));
            float al0 = fminf(ALPHA_MAX_C, exp2f(p0));
            float al1 = fminf(ALPHA_MAX_C, exp2f(p1));
            float al2 = fminf(ALPHA_MAX_C, exp2f(p2));
            float al3 = fminf(ALPHA_MAX_C, exp2f(p3));
            al0 = (al0 >= ALPHA_MIN_C) ? al0 : 0.0f;
            al1 = (al1 >= ALPHA_MIN_C) ? al1 : 0.0f;
            al2 = (al2 >= ALPHA_MIN_C) ? al2 : 0.0f;
            al3 = (al3 >= ALPHA_MIN_C) ? al3 : 0.0f;
            if (__any((al0 > 0.f) | (al1 > 0.f) | (al2 > 0.f) | (al3 > 0.f))) {
                unsigned cu = __float_as_uint(r1.y);
                __half2 ch; __builtin_memcpy(&ch, &cu, 4);
                float cr = __half2float(ch.x);
                float cg = __half2float(ch.y);
                float cb = r1.z;
                float s0 = al0*T0, s1 = al1*T1, s2 = al2*T2, s3 = al3*T3;
                aR0 = fmaf(cr,s0,aR0); aG0 = fmaf(cg,s0,aG0); aB0 = fmaf(cb,s0,aB0);
                aR1 = fmaf(cr,s1,aR1); aG1 = fmaf(cg,s1,aG1); aB1 = fmaf(cb,s1,aB1);
                aR2 = fmaf(cr,s2,aR2); aG2 = fmaf(cg,s2,aG2); aB2 = fmaf(cb,s2,aB2);
                aR3 = fmaf(cr,s3,aR3); aG3 = fmaf(cg,s3,aG3); aB3 = fmaf(cb,s3,aB3);
                T0 = fmaf(-al0,T0,T0); T1 = fmaf(-al1,T1,T1);
                T2 = fmaf(-al2,T2,T2); T3 = fmaf(-al3,T3,T3);
            }
            r0 = r0N; r1 = r1N; gi = giN;
        }
    }
    const int pix0 = py*WW + px;
    uint2* sb = segbuf + seg * NPIX;
    sb[pix0        ] = packAT(aR0, aG0, aB0, T0);
    sb[pix0 +  4*WW] = packAT(aR1, aG1, aB1, T1);
    sb[pix0 +  8*WW] = packAT(aR2, aG2, aB2, T2);
    sb[pix0 + 12*WW] = packAT(aR3, aG3, aB3, T3);
}

// ---------------- Kernel 5: composite segments front-to-back ------------------
__global__ __launch_bounds__(256) void composite_kernel(
    const uint2* __restrict__ segbuf, const float* __restrict__ bg,
    float* __restrict__ out) {
    const int pix = blockIdx.x * 256 + threadIdx.x;
    float R = 0.f, G = 0.f, B = 0.f, T = 1.f;
#pragma unroll
    for (int s = 0; s < NSEG; ++s) {
        uint2 v = segbuf[s * NPIX + pix];
        __half2 hrg, hbt;
        __builtin_memcpy(&hrg, &v.x, 4);
        __builtin_memcpy(&hbt, &v.y, 4);
        R = fmaf(T, __half2float(hrg.x), R);
        G = fmaf(T, __half2float(hrg.y), G);
        B = fmaf(T, __half2float(hbt.x), B);
        T *= __half2float(hbt.y);
    }
    out[pix]          = R + bg[0]*T;
    out[pix +   NPIX] = G + bg[1]*T;
    out[pix + 2*NPIX] = B + bg[2]*T;
}

extern "C" void kernel_launch(void* const* d_in, const int* in_sizes, int n_in,
                              void* d_out, int out_size, void* d_ws, size_t ws_size,
                              hipStream_t stream) {
    const float* means   = (const float*)d_in[0];
    const float* colors  = (const float*)d_in[1];
    const float* ops     = (const float*)d_in[2];
    const float* scales  = (const float*)d_in[3];
    const float* rots    = (const float*)d_in[4];
    const float* depths  = (const float*)d_in[5];
    const float* bg      = (const float*)d_in[6];
    const int N = in_sizes[0] / 2;           // 8192

    char* ws = (char*)d_ws;
    float4*   pP    = (float4*)(ws);                        // N*16
    float4*   pR0   = (float4*)(ws + (size_t)N*16);         // N*16
    float4*   pR1   = (float4*)(ws + (size_t)N*32);         // N*16
    int*      part  = (int*)   (ws + (size_t)N*48);         // 16*N*4
    uint32_t* masks = (uint32_t*)(ws + (size_t)N*112);      // 8*1024*128 = 1 MB
    uint2*    segb  = (uint2*) (ws + (size_t)N*112 + (size_t)NSEG*1024*128);  // 16 MB

    hipMemsetAsync(masks, 0, (size_t)NSEG*1024*128, stream);

    const int ngb = N / 256;                 // 32
    const int njb = N / JSL;                 // 16
    rank_kernel<<<dim3(ngb*njb), dim3(256), 0, stream>>>(depths, N, part);
    prep_kernel<<<dim3((N+255)/256), dim3(256), 0, stream>>>(
        means, colors, ops, scales, rots, part, N, pP, pR0, pR1);
    bin_kernel<<<dim3((N+255)/256), dim3(256), 0, stream>>>(pP, masks, N);
    seg_blend_kernel<<<dim3(NSEG*1024), dim3(64), 0, stream>>>(pR0, pR1, masks, segb);
    composite_kernel<<<dim3(NPIX/256), dim3(256), 0, stream>>>(
        segb, bg, (float*)d_out);
}

// Round 14
// 133.719 us; speedup vs baseline: 1.0278x; 1.0278x over previous
//
#include <hip/hip_runtime.h>
#include <hip/hip_fp16.h>
#include <stdint.h>

#define HH 512
#define WW 512
#define NPIX (HH*WW)
#define ALPHA_MIN_C (1.0f/255.0f)
#define ALPHA_MAX_C 0.99f
#define BLUR_C 0.3f
#define LOG2E 1.4426950408889634f

#define NSEG 4
#define SEGG 2048
#define MASKW 64                      // words per (tile,seg) mask = SEGG/32
#define TOTMASKW (NSEG*1024*MASKW)    // 262144 words = 1 MB

// ---------------- Kernel 1: partial stable-rank counts + mask clear -----------
// rank[g] = #{ j : d[j] < d[g] or (d[j]==d[g] and j<g) }  (JAX stable argsort)
// Also clears the bin masks (stream order: rank -> prep -> bin).
#define JSL 512
__global__ __launch_bounds__(256) void rank_kernel(const float* __restrict__ depths,
                                                   int N, int* __restrict__ partial,
                                                   uint32_t* __restrict__ masks) {
    __shared__ uint32_t sk[JSL];
    const int tid = threadIdx.x;
    // grid-stride mask clear (131072 threads over 262144 words)
    const int gid = blockIdx.x * 256 + tid;
    const int gsz = gridDim.x * 256;
    for (int i = gid; i < TOTMASKW; i += gsz) masks[i] = 0u;

    const int ngb = N >> 8;                       // 32
    const int gb = blockIdx.x % ngb;
    const int jb = blockIdx.x / ngb;
    const int j0 = jb * JSL;
    for (int i = tid; i < JSL; i += 256)
        sk[i] = __float_as_uint(depths[j0 + i]);
    __syncthreads();
    const int g = gb * 256 + tid;
    const uint32_t mb = __float_as_uint(depths[g]);
    const int glim = g - j0;                      // tie j0+i < g  <=>  i < glim
    int cnt = 0;
    const uint4* sk4 = (const uint4*)sk;
#pragma unroll 8
    for (int q = 0; q < JSL / 4; ++q) {
        uint4 v = sk4[q];
        const int i4 = q * 4;
        cnt += (v.x < mb) || (v.x == mb && (i4 + 0) < glim);
        cnt += (v.y < mb) || (v.y == mb && (i4 + 1) < glim);
        cnt += (v.z < mb) || (v.z == mb && (i4 + 2) < glim);
        cnt += (v.w < mb) || (v.w == mb && (i4 + 3) < glim);
    }
    partial[jb * N + g] = cnt;
}

// ---------------- Kernel 2: prep + scatter into sorted order ------------------
// pP [pos] = (mx, my, bx, by)                 (AABB, used only by bin_kernel)
// pR0[pos] = (mx, my, iaF, ibF|icF f16x2)
// pR1[pos] = (lop, cr|cg f16x2, cb, 0)
// alpha = min(.99, exp2(iaF dx^2 + icF dy^2 + ibF dx dy + lop)), lop = log2(op)
// AABB exact marginal bound: alpha>=1/255 requires |dx|<=bx AND |dy|<=by.
__global__ __launch_bounds__(256) void prep_kernel(
    const float* __restrict__ means, const float* __restrict__ colors,
    const float* __restrict__ ops, const float* __restrict__ scales,
    const float* __restrict__ rots, const int* __restrict__ partial, int N,
    float4* __restrict__ pP, float4* __restrict__ pR0, float4* __restrict__ pR1) {
    int g = blockIdx.x * 256 + threadIdx.x;
    if (g >= N) return;
    int pos = 0;
#pragma unroll
    for (int s = 0; s < 16; ++s) pos += partial[s * N + g];
    float mx = means[2*g], my = means[2*g+1];
    float th = rots[g];
    float c = cosf(th), si = sinf(th);
    float sx = scales[2*g], sy = scales[2*g+1];
    float sx2 = sx*sx, sy2 = sy*sy;
    float A  = c*c*sx2 + si*si*sy2;
    float Cc = si*si*sx2 + c*c*sy2;
    float B  = c*si*(sx2 - sy2);
    float det = A*Cc - B*B;
    float A2 = A + BLUR_C, C2 = Cc + BLUR_C;      // dilated Sxx, Syy
    float det2 = A2*C2 - B*B;
    float op = ops[g] * sqrtf(fmaxf(det/det2, 0.0f));
    float invd = 1.0f/det2;
    float ia = C2*invd, ib = -B*invd, ic = A2*invd;       // Sigma^-1
    float iaF = -0.5f*LOG2E*ia, icF = -0.5f*LOG2E*ic, ibF = -LOG2E*ib;
    float bx, by, lop;
    if (op < ALPHA_MIN_C) {
        bx = -1.0f; by = -1.0f; lop = -128.0f;
    } else {
        float t = __logf(op * 255.0f);                    // ln(op/ALPHA_MIN) >= 0
        bx = sqrtf(fmaxf(2.0f * t * A2, 0.0f)) * 1.0001f + 0.1f;
        by = sqrtf(fmaxf(2.0f * t * C2, 0.0f)) * 1.0001f + 0.1f;
        lop = __log2f(op);
    }
    __half2 h2 = __floats2half2_rn(ibF, icF);
    unsigned ibic; __builtin_memcpy(&ibic, &h2, 4);
    __half2 cc = __floats2half2_rn(colors[3*g], colors[3*g+1]);
    unsigned crcg; __builtin_memcpy(&crcg, &cc, 4);
    pP [pos] = make_float4(mx, my, bx, by);
    pR0[pos] = make_float4(mx, my, iaF, __uint_as_float(ibic));
    pR1[pos] = make_float4(lop, __uint_as_float(crcg), colors[3*g+2], 0.0f);
}

// ---------------- Kernel 3: bitmask binning -----------------------------------
// For sorted gaussian p: set bit (p % SEGG) in the mask of every tile whose
// pixel-center rect overlaps the AABB. Bit order == depth order.
__global__ __launch_bounds__(256) void bin_kernel(
    const float4* __restrict__ pP, uint32_t* __restrict__ masks, int N) {
    int p = blockIdx.x * 256 + threadIdx.x;
    if (p >= N) return;
    float4 a = pP[p];
    if (a.z < 0.0f) return;
    int tx0 = max(0,  (int)ceilf ((a.x - a.z - 15.5f) * 0.0625f));
    int tx1 = min(31, (int)floorf((a.x + a.z -  0.5f) * 0.0625f));
    int ty0 = max(0,  (int)ceilf ((a.y - a.w - 15.5f) * 0.0625f));
    int ty1 = min(31, (int)floorf((a.y + a.w -  0.5f) * 0.0625f));
    const int seg = p >> 11;                      // /SEGG
    const int bit = p & (SEGG - 1);
    const uint32_t wi = bit >> 5;
    const uint32_t bm = 1u << (bit & 31);
    uint32_t* base = masks + (((uint32_t)seg << 10) * MASKW) + wi;
    for (int ty = ty0; ty <= ty1; ++ty)
        for (int tx = tx0; tx <= tx1; ++tx)
            atomicOr(base + (uint32_t)(ty*32 + tx) * MASKW, bm);
}

// ---------------- Kernel 4: depth-segmented blend (mask-driven) ---------------
// 4 seg x 1024 tiles = 4096 one-wave blocks, 4 px/lane (rows y,y+4,y+8,y+12).
// Block reads its 2048-bit mask (1 word/lane), wave-scans set bits into an
// ordered LDS index list (4KB), then blends only the listed records via
// broadcast global loads (software-pipelined 1 ahead). Segment (A_rgb,T)
// packed 4xf16; composite folds segments in depth order (associativity).
__device__ __forceinline__ uint2 packAT(float r, float g, float b, float t) {
    __half2 hrg = __floats2half2_rn(r, g);
    __half2 hbt = __floats2half2_rn(b, t);
    uint2 u;
    __builtin_memcpy(&u.x, &hrg, 4);
    __builtin_memcpy(&u.y, &hbt, 4);
    return u;
}

__global__ __launch_bounds__(64) void seg_blend_kernel(
    const float4* __restrict__ pR0, const float4* __restrict__ pR1,
    const uint32_t* __restrict__ masks, uint2* __restrict__ segbuf) {
    __shared__ uint16_t sIdx[SEGG];
    const int lane = threadIdx.x;                 // 0..63
    const int tile = blockIdx.x & 1023;
    const int seg  = blockIdx.x >> 10;            // 0..3
    const int tX = tile & 31, tY = tile >> 5;
    const int px = tX*16 + (lane & 15);
    const int py = tY*16 + (lane >> 4);           // rows 0..3 (+4k below)
    const float fx = px + 0.5f, fy = py + 0.5f;

    // ---- ordered index list from the mask (1 word per lane) ----
    uint32_t w = masks[(((uint32_t)seg << 10) | tile)*MASKW + lane];
    int pc = __popc(w);
    int inc = pc;
#pragma unroll
    for (int d = 1; d < 64; d <<= 1) {
        int t = __shfl_up(inc, d);
        if (lane >= d) inc += t;
    }
    const int M = __shfl(inc, 63);
    int off = inc - pc;
    const int bword = lane << 5;
    while (w) {
        int b = __ffs(w) - 1;
        w &= w - 1;
        sIdx[off++] = (uint16_t)(bword + b);
    }
    __threadfence_block();                        // list visible to the wave

    float T0=1.f,T1=1.f,T2=1.f,T3=1.f;
    float aR0=0.f,aG0=0.f,aB0=0.f;
    float aR1=0.f,aG1=0.f,aB1=0.f;
    float aR2=0.f,aG2=0.f,aB2=0.f;
    float aR3=0.f,aG3=0.f,aB3=0.f;
    const int gb = seg << 11;                     // seg*SEGG

    if (M > 0) {
        int gi = gb + sIdx[0];
        float4 r0 = pR0[gi];
        float4 r1 = pR1[gi];
        for (int i = 0; i < M; ++i) {
            // issue next record's loads before evaluating current (pipelined)
            int giN = gi;
            if (i + 1 < M) giN = gb + sIdx[i + 1];
            float4 r0N = pR0[giN];
            float4 r1N = pR1[giN];
            float dx = fx - r0.x;
            float dy = fy - r0.y;
            unsigned hh = __float_as_uint(r0.w);
            __half2 h2; __builtin_memcpy(&h2, &hh, 4);
            float ibv = __half2float(h2.x);
            float icv = __half2float(h2.y);
            float bse = fmaf(r0.z, dx*dx, r1.x);     // iaF*dx^2 + lop
            float pb  = ibv * dx;                    // ibF*dx (shared by 4 rows)
            float d1 = dy + 4.0f, d2 = dy + 8.0f, d3 = dy + 12.0f;
            float p0 = fmaf(icv, dy*dy, fmaf(pb, dy, bse));
            float p1 = fmaf(icv, d1*d1, fmaf(pb, d1, bse));
            float p2 = fmaf(icv, d2*d2, fmaf(pb, d2, bse));
            float p3 = fmaf(icv, d3*d3, fmaf(pb, d3, bse));
            float al0 = fminf(ALPHA_MAX_C, exp2f(p0));
            float al1 = fminf(ALPHA_MAX_C, exp2f(p1));
            float al2 = fminf(ALPHA_MAX_C, exp2f(p2));
            float al3 = fminf(ALPHA_MAX_C, exp2f(p3));
            al0 = (al0 >= ALPHA_MIN_C) ? al0 : 0.0f;
            al1 = (al1 >= ALPHA_MIN_C) ? al1 : 0.0f;
            al2 = (al2 >= ALPHA_MIN_C) ? al2 : 0.0f;
            al3 = (al3 >= ALPHA_MIN_C) ? al3 : 0.0f;
            if (__any((al0 > 0.f) | (al1 > 0.f) | (al2 > 0.f) | (al3 > 0.f))) {
                unsigned cu = __float_as_uint(r1.y);
                __half2 ch; __builtin_memcpy(&ch, &cu, 4);
                float cr = __half2float(ch.x);
                float cg = __half2float(ch.y);
                float cb = r1.z;
                float s0 = al0*T0, s1 = al1*T1, s2 = al2*T2, s3 = al3*T3;
                aR0 = fmaf(cr,s0,aR0); aG0 = fmaf(cg,s0,aG0); aB0 = fmaf(cb,s0,aB0);
                aR1 = fmaf(cr,s1,aR1); aG1 = fmaf(cg,s1,aG1); aB1 = fmaf(cb,s1,aB1);
                aR2 = fmaf(cr,s2,aR2); aG2 = fmaf(cg,s2,aG2); aB2 = fmaf(cb,s2,aB2);
                aR3 = fmaf(cr,s3,aR3); aG3 = fmaf(cg,s3,aG3); aB3 = fmaf(cb,s3,aB3);
                T0 = fmaf(-al0,T0,T0); T1 = fmaf(-al1,T1,T1);
                T2 = fmaf(-al2,T2,T2); T3 = fmaf(-al3,T3,T3);
            }
            r0 = r0N; r1 = r1N; gi = giN;
        }
    }
    const int pix0 = py*WW + px;
    uint2* sb = segbuf + seg * NPIX;
    sb[pix0        ] = packAT(aR0, aG0, aB0, T0);
    sb[pix0 +  4*WW] = packAT(aR1, aG1, aB1, T1);
    sb[pix0 +  8*WW] = packAT(aR2, aG2, aB2, T2);
    sb[pix0 + 12*WW] = packAT(aR3, aG3, aB3, T3);
}

// ---------------- Kernel 5: composite segments front-to-back ------------------
__global__ __launch_bounds__(256) void composite_kernel(
    const uint2* __restrict__ segbuf, const float* __restrict__ bg,
    float* __restrict__ out) {
    const int pix = blockIdx.x * 256 + threadIdx.x;
    float R = 0.f, G = 0.f, B = 0.f, T = 1.f;
#pragma unroll
    for (int s = 0; s < NSEG; ++s) {
        uint2 v = segbuf[s * NPIX + pix];
        __half2 hrg, hbt;
        __builtin_memcpy(&hrg, &v.x, 4);
        __builtin_memcpy(&hbt, &v.y, 4);
        R = fmaf(T, __half2float(hrg.x), R);
        G = fmaf(T, __half2float(hrg.y), G);
        B = fmaf(T, __half2float(hbt.x), B);
        T *= __half2float(hbt.y);
    }
    out[pix]          = R + bg[0]*T;
    out[pix +   NPIX] = G + bg[1]*T;
    out[pix + 2*NPIX] = B + bg[2]*T;
}

extern "C" void kernel_launch(void* const* d_in, const int* in_sizes, int n_in,
                              void* d_out, int out_size, void* d_ws, size_t ws_size,
                              hipStream_t stream) {
    const float* means   = (const float*)d_in[0];
    const float* colors  = (const float*)d_in[1];
    const float* ops     = (const float*)d_in[2];
    const float* scales  = (const float*)d_in[3];
    const float* rots    = (const float*)d_in[4];
    const float* depths  = (const float*)d_in[5];
    const float* bg      = (const float*)d_in[6];
    const int N = in_sizes[0] / 2;           // 8192

    char* ws = (char*)d_ws;
    float4*   pP    = (float4*)(ws);                        // N*16
    float4*   pR0   = (float4*)(ws + (size_t)N*16);         // N*16
    float4*   pR1   = (float4*)(ws + (size_t)N*32);         // N*16
    int*      part  = (int*)   (ws + (size_t)N*48);         // 16*N*4
    uint32_t* masks = (uint32_t*)(ws + (size_t)N*112);      // 1 MB
    uint2*    segb  = (uint2*) (ws + (size_t)N*112 + (size_t)TOTMASKW*4);  // 8 MB

    const int ngb = N / 256;                 // 32
    const int njb = N / JSL;                 // 16
    rank_kernel<<<dim3(ngb*njb), dim3(256), 0, stream>>>(depths, N, part, masks);
    prep_kernel<<<dim3((N+255)/256), dim3(256), 0, stream>>>(
        means, colors, ops, scales, rots, part, N, pP, pR0, pR1);
    bin_kernel<<<dim3((N+255)/256), dim3(256), 0, stream>>>(pP, masks, N);
    seg_blend_kernel<<<dim3(NSEG*1024), dim3(64), 0, stream>>>(pR0, pR1, masks, segb);
    composite_kernel<<<dim3(NPIX/256), dim3(256), 0, stream>>>(
        segb, bg, (float*)d_out);
}

// Round 15
// 132.296 us; speedup vs baseline: 1.0388x; 1.0108x over previous
//
#include <hip/hip_runtime.h>
#include <hip/hip_fp16.h>
#include <stdint.h>

#define HH 512
#define WW 512
#define NPIX (HH*WW)
#define ALPHA_MIN_C (1.0f/255.0f)
#define ALPHA_MAX_C 0.99f
#define BLUR_C 0.3f
#define LOG2E 1.4426950408889634f

#define NSEG 4
#define SEGG 2048
#define MASKW 64                      // words per (tile,seg) mask = SEGG/32
#define TOTMASKW (NSEG*1024*MASKW)    // 262144 words = 1 MB

// ---------------- Kernel 1: partial stable-rank counts + mask clear -----------
// rank[g] = #{ j : d[j] < d[g] or (d[j]==d[g] and j<g) }  (JAX stable argsort)
// Also clears the bin masks (stream order: rank -> prep/bin).
#define JSL 512
__global__ __launch_bounds__(256) void rank_kernel(const float* __restrict__ depths,
                                                   int N, int* __restrict__ partial,
                                                   uint32_t* __restrict__ masks) {
    __shared__ uint32_t sk[JSL];
    const int tid = threadIdx.x;
    // grid-stride mask clear (131072 threads over 262144 words)
    const int gid = blockIdx.x * 256 + tid;
    const int gsz = gridDim.x * 256;
    for (int i = gid; i < TOTMASKW; i += gsz) masks[i] = 0u;

    const int ngb = N >> 8;                       // 32
    const int gb = blockIdx.x % ngb;
    const int jb = blockIdx.x / ngb;
    const int j0 = jb * JSL;
    for (int i = tid; i < JSL; i += 256)
        sk[i] = __float_as_uint(depths[j0 + i]);
    __syncthreads();
    const int g = gb * 256 + tid;
    const uint32_t mb = __float_as_uint(depths[g]);
    const int glim = g - j0;                      // tie j0+i < g  <=>  i < glim
    int cnt = 0;
    const uint4* sk4 = (const uint4*)sk;
#pragma unroll 8
    for (int q = 0; q < JSL / 4; ++q) {
        uint4 v = sk4[q];
        const int i4 = q * 4;
        cnt += (v.x < mb) || (v.x == mb && (i4 + 0) < glim);
        cnt += (v.y < mb) || (v.y == mb && (i4 + 1) < glim);
        cnt += (v.z < mb) || (v.z == mb && (i4 + 2) < glim);
        cnt += (v.w < mb) || (v.w == mb && (i4 + 3) < glim);
    }
    partial[jb * N + g] = cnt;
}

// ---------------- Kernel 2: prep + scatter + FUSED binning --------------------
// pR0[pos] = (mx, my, iaF, ibF|icF f16x2)
// pR1[pos] = (lop, cr|cg f16x2, cb, 0)
// alpha = min(.99, exp2(iaF dx^2 + icF dy^2 + ibF dx dy + lop)), lop = log2(op)
// AABB (exact marginal bound): alpha>=1/255 requires |dx|<=bx AND |dy|<=by,
// bx = sqrt(2 ln(255 op) Sxx). Sets bit (pos % SEGG) in every overlapped
// tile's (tile,seg) mask. Bit order == depth order.
__global__ __launch_bounds__(256) void prep_kernel(
    const float* __restrict__ means, const float* __restrict__ colors,
    const float* __restrict__ ops, const float* __restrict__ scales,
    const float* __restrict__ rots, const int* __restrict__ partial, int N,
    float4* __restrict__ pR0, float4* __restrict__ pR1,
    uint32_t* __restrict__ masks) {
    int g = blockIdx.x * 256 + threadIdx.x;
    if (g >= N) return;
    int pos = 0;
#pragma unroll
    for (int s = 0; s < 16; ++s) pos += partial[s * N + g];
    float mx = means[2*g], my = means[2*g+1];
    float th = rots[g];
    float c = cosf(th), si = sinf(th);
    float sx = scales[2*g], sy = scales[2*g+1];
    float sx2 = sx*sx, sy2 = sy*sy;
    float A  = c*c*sx2 + si*si*sy2;
    float Cc = si*si*sx2 + c*c*sy2;
    float B  = c*si*(sx2 - sy2);
    float det = A*Cc - B*B;
    float A2 = A + BLUR_C, C2 = Cc + BLUR_C;      // dilated Sxx, Syy
    float det2 = A2*C2 - B*B;
    float op = ops[g] * sqrtf(fmaxf(det/det2, 0.0f));
    float invd = 1.0f/det2;
    float ia = C2*invd, ib = -B*invd, ic = A2*invd;       // Sigma^-1
    float iaF = -0.5f*LOG2E*ia, icF = -0.5f*LOG2E*ic, ibF = -LOG2E*ib;
    float bx, by, lop;
    bool vis = (op >= ALPHA_MIN_C);
    if (!vis) {
        bx = -1.0f; by = -1.0f; lop = -128.0f;
    } else {
        float t = __logf(op * 255.0f);                    // ln(op/ALPHA_MIN) >= 0
        bx = sqrtf(fmaxf(2.0f * t * A2, 0.0f)) * 1.0001f + 0.1f;
        by = sqrtf(fmaxf(2.0f * t * C2, 0.0f)) * 1.0001f + 0.1f;
        lop = __log2f(op);
    }
    __half2 h2 = __floats2half2_rn(ibF, icF);
    unsigned ibic; __builtin_memcpy(&ibic, &h2, 4);
    __half2 cc = __floats2half2_rn(colors[3*g], colors[3*g+1]);
    unsigned crcg; __builtin_memcpy(&crcg, &cc, 4);
    pR0[pos] = make_float4(mx, my, iaF, __uint_as_float(ibic));
    pR1[pos] = make_float4(lop, __uint_as_float(crcg), colors[3*g+2], 0.0f);
    // ---- fused binning ----
    if (vis) {
        int tx0 = max(0,  (int)ceilf ((mx - bx - 15.5f) * 0.0625f));
        int tx1 = min(31, (int)floorf((mx + bx -  0.5f) * 0.0625f));
        int ty0 = max(0,  (int)ceilf ((my - by - 15.5f) * 0.0625f));
        int ty1 = min(31, (int)floorf((my + by -  0.5f) * 0.0625f));
        const int seg = pos >> 11;                    // /SEGG
        const int bit = pos & (SEGG - 1);
        const uint32_t wi = bit >> 5;
        const uint32_t bm = 1u << (bit & 31);
        uint32_t* base = masks + (((uint32_t)seg << 10) * MASKW) + wi;
        for (int ty = ty0; ty <= ty1; ++ty)
            for (int tx = tx0; tx <= tx1; ++tx)
                atomicOr(base + (uint32_t)(ty*32 + tx) * MASKW, bm);
    }
}

// ---------------- Kernel 3: depth-segmented blend (mask-driven) ---------------
// 4 seg x 1024 tiles = 4096 one-wave blocks, 4 px/lane (rows y,y+4,y+8,y+12).
// Block reads its 2048-bit mask (1 word/lane), wave-scans set bits into an
// ordered LDS index list (4KB), then blends only the listed records via
// broadcast global loads (software-pipelined 1 ahead). Segment (A_rgb,T)
// packed 4xf16; composite folds segments in depth order (associativity).
__device__ __forceinline__ uint2 packAT(float r, float g, float b, float t) {
    __half2 hrg = __floats2half2_rn(r, g);
    __half2 hbt = __floats2half2_rn(b, t);
    uint2 u;
    __builtin_memcpy(&u.x, &hrg, 4);
    __builtin_memcpy(&u.y, &hbt, 4);
    return u;
}

__global__ __launch_bounds__(64) void seg_blend_kernel(
    const float4* __restrict__ pR0, const float4* __restrict__ pR1,
    const uint32_t* __restrict__ masks, uint2* __restrict__ segbuf) {
    __shared__ uint16_t sIdx[SEGG];
    const int lane = threadIdx.x;                 // 0..63
    const int tile = blockIdx.x & 1023;
    const int seg  = blockIdx.x >> 10;            // 0..3
    const int tX = tile & 31, tY = tile >> 5;
    const int px = tX*16 + (lane & 15);
    const int py = tY*16 + (lane >> 4);           // rows 0..3 (+4k below)
    const float fx = px + 0.5f, fy = py + 0.5f;

    // ---- ordered index list from the mask (1 word per lane) ----
    uint32_t w = masks[(((uint32_t)seg << 10) | tile)*MASKW + lane];
    int pc = __popc(w);
    int inc = pc;
#pragma unroll
    for (int d = 1; d < 64; d <<= 1) {
        int t = __shfl_up(inc, d);
        if (lane >= d) inc += t;
    }
    const int M = __shfl(inc, 63);
    int off = inc - pc;
    const int bword = lane << 5;
    while (w) {
        int b = __ffs(w) - 1;
        w &= w - 1;
        sIdx[off++] = (uint16_t)(bword + b);
    }
    __threadfence_block();                        // list visible to the wave

    float T0=1.f,T1=1.f,T2=1.f,T3=1.f;
    float aR0=0.f,aG0=0.f,aB0=0.f;
    float aR1=0.f,aG1=0.f,aB1=0.f;
    float aR2=0.f,aG2=0.f,aB2=0.f;
    float aR3=0.f,aG3=0.f,aB3=0.f;
    const int gb = seg << 11;                     // seg*SEGG

    if (M > 0) {
        int gi = gb + sIdx[0];
        float4 r0 = pR0[gi];
        float4 r1 = pR1[gi];
        for (int i = 0; i < M; ++i) {
            // issue next record's loads before evaluating current (pipelined)
            int giN = gi;
            if (i + 1 < M) giN = gb + sIdx[i + 1];
            float4 r0N = pR0[giN];
            float4 r1N = pR1[giN];
            float dx = fx - r0.x;
            float dy = fy - r0.y;
            unsigned hh = __float_as_uint(r0.w);
            __half2 h2; __builtin_memcpy(&h2, &hh, 4);
            float ibv = __half2float(h2.x);
            float icv = __half2float(h2.y);
            float bse = fmaf(r0.z, dx*dx, r1.x);     // iaF*dx^2 + lop
            float pb  = ibv * dx;                    // ibF*dx (shared by 4 rows)
            float d1 = dy + 4.0f, d2 = dy + 8.0f, d3 = dy + 12.0f;
            float p0 = fmaf(icv, dy*dy, fmaf(pb, dy, bse));
            float p1 = fmaf(icv, d1*d1, fmaf(pb, d1, bse));
            float p2 = fmaf(icv, d2*d2, fmaf(pb, d2, bse));
            float p3 = fmaf(icv, d3*d3, fmaf(pb, d3, bse));
            float al0 = fminf(ALPHA_MAX_C, exp2f(p0));
            float al1 = fminf(ALPHA_MAX_C, exp2f(p1));
            float al2 = fminf(ALPHA_MAX_C, exp2f(p2));
            float al3 = fminf(ALPHA_MAX_C, exp2f(p3));
            al0 = (al0 >= ALPHA_MIN_C) ? al0 : 0.0f;
            al1 = (al1 >= ALPHA_MIN_C) ? al1 : 0.0f;
            al2 = (al2 >= ALPHA_MIN_C) ? al2 : 0.0f;
            al3 = (al3 >= ALPHA_MIN_C) ? al3 : 0.0f;
            if (__any((al0 > 0.f) | (al1 > 0.f) | (al2 > 0.f) | (al3 > 0.f))) {
                unsigned cu = __float_as_uint(r1.y);
                __half2 ch; __builtin_memcpy(&ch, &cu, 4);
                float cr = __half2float(ch.x);
                float cg = __half2float(ch.y);
                float cb = r1.z;
                float s0 = al0*T0, s1 = al1*T1, s2 = al2*T2, s3 = al3*T3;
                aR0 = fmaf(cr,s0,aR0); aG0 = fmaf(cg,s0,aG0); aB0 = fmaf(cb,s0,aB0);
                aR1 = fmaf(cr,s1,aR1); aG1 = fmaf(cg,s1,aG1); aB1 = fmaf(cb,s1,aB1);
                aR2 = fmaf(cr,s2,aR2); aG2 = fmaf(cg,s2,aG2); aB2 = fmaf(cb,s2,aB2);
                aR3 = fmaf(cr,s3,aR3); aG3 = fmaf(cg,s3,aG3); aB3 = fmaf(cb,s3,aB3);
                T0 = fmaf(-al0,T0,T0); T1 = fmaf(-al1,T1,T1);
                T2 = fmaf(-al2,T2,T2); T3 = fmaf(-al3,T3,T3);
            }
            r0 = r0N; r1 = r1N; gi = giN;
        }
    }
    const int pix0 = py*WW + px;
    uint2* sb = segbuf + seg * NPIX;
    sb[pix0        ] = packAT(aR0, aG0, aB0, T0);
    sb[pix0 +  4*WW] = packAT(aR1, aG1, aB1, T1);
    sb[pix0 +  8*WW] = packAT(aR2, aG2, aB2, T2);
    sb[pix0 + 12*WW] = packAT(aR3, aG3, aB3, T3);
}

// ---------------- Kernel 4: composite segments front-to-back ------------------
__global__ __launch_bounds__(256) void composite_kernel(
    const uint2* __restrict__ segbuf, const float* __restrict__ bg,
    float* __restrict__ out) {
    const int pix = blockIdx.x * 256 + threadIdx.x;
    float R = 0.f, G = 0.f, B = 0.f, T = 1.f;
#pragma unroll
    for (int s = 0; s < NSEG; ++s) {
        uint2 v = segbuf[s * NPIX + pix];
        __half2 hrg, hbt;
        __builtin_memcpy(&hrg, &v.x, 4);
        __builtin_memcpy(&hbt, &v.y, 4);
        R = fmaf(T, __half2float(hrg.x), R);
        G = fmaf(T, __half2float(hrg.y), G);
        B = fmaf(T, __half2float(hbt.x), B);
        T *= __half2float(hbt.y);
    }
    out[pix]          = R + bg[0]*T;
    out[pix +   NPIX] = G + bg[1]*T;
    out[pix + 2*NPIX] = B + bg[2]*T;
}

extern "C" void kernel_launch(void* const* d_in, const int* in_sizes, int n_in,
                              void* d_out, int out_size, void* d_ws, size_t ws_size,
                              hipStream_t stream) {
    const float* means   = (const float*)d_in[0];
    const float* colors  = (const float*)d_in[1];
    const float* ops     = (const float*)d_in[2];
    const float* scales  = (const float*)d_in[3];
    const float* rots    = (const float*)d_in[4];
    const float* depths  = (const float*)d_in[5];
    const float* bg      = (const float*)d_in[6];
    const int N = in_sizes[0] / 2;           // 8192

    char* ws = (char*)d_ws;
    float4*   pR0   = (float4*)(ws);                        // N*16
    float4*   pR1   = (float4*)(ws + (size_t)N*16);         // N*16
    int*      part  = (int*)   (ws + (size_t)N*32);         // 16*N*4 = N*64
    uint32_t* masks = (uint32_t*)(ws + (size_t)N*96);       // 1 MB
    uint2*    segb  = (uint2*) (ws + (size_t)N*96 + (size_t)TOTMASKW*4);  // 8 MB

    const int ngb = N / 256;                 // 32
    const int njb = N / JSL;                 // 16
    rank_kernel<<<dim3(ngb*njb), dim3(256), 0, stream>>>(depths, N, part, masks);
    prep_kernel<<<dim3((N+255)/256), dim3(256), 0, stream>>>(
        means, colors, ops, scales, rots, part, N, pR0, pR1, masks);
    seg_blend_kernel<<<dim3(NSEG*1024), dim3(64), 0, stream>>>(pR0, pR1, masks, segb);
    composite_kernel<<<dim3(NPIX/256), dim3(256), 0, stream>>>(
        segb, bg, (float*)d_out);
}